// Round 11
// baseline (2000.598 us; speedup 1.0000x reference)
//
#include <hip/hip_runtime.h>
#include <hip/hip_fp16.h>
#include <hip/hip_cooperative_groups.h>

namespace cg = cooperative_groups;

// Problem constants (from reference)
#define FDIM 512
#define TDK  0.1f   // TIME_DECAY
#define DTs  0.2f   // DIFF_T / NUM_STEPS
#define EPSv 1e-5f

using bf16x8  = __attribute__((ext_vector_type(8))) __bf16;
using floatx4 = __attribute__((ext_vector_type(4))) float;
using ushort8 = __attribute__((ext_vector_type(8))) unsigned short;
using uintx4  = __attribute__((ext_vector_type(4))) unsigned int;   // native vec for nontemporal builtins

__device__ __forceinline__ unsigned short f2bf(float f) {
  unsigned int u = __float_as_uint(f);
  u += 0x7fffu + ((u >> 16) & 1u);   // RNE
  return (unsigned short)(u >> 16);
}

// async global->LDS, 16 B per lane; LDS dest = wave-uniform base + lane*16
__device__ __forceinline__ void gld16(const __bf16* g, __bf16* l) {
  __builtin_amdgcn_global_load_lds(
      (const __attribute__((address_space(1))) unsigned int*)g,
      (__attribute__((address_space(3))) unsigned int*)l, 16, 0, 0);
}

// ================= COOPERATIVE PROLOGUE: 6 kernels -> 1 launch ===============
// r10 analysis: ~95 us of the 354 us total was inter-dispatch launch overhead
// (17 dispatches x ~5-6 us). This kernel replaces edge_w_deg + cast_all +
// seg_reduce + scan_bsum + seg_scan + scatter with one cooperative launch and
// 4 grid.sync()s. Phase A co-schedules the atomic-bound edge pass with the
// BW-bound casts (independent) so their latencies overlap.
// All per-kernel algorithms unchanged from r8/r10 (measured-good):
//  - ts.max() eliminated algebraically (w = exp(TDK*(t-gt)), cancels in ew)
//  - ONE packed 64-bit atomic: bits52+ = count, bits0..51 = fixed-point deg
//  - counts padded to x4 (pad cv slots are zero: src 0, weight fp16(0) -> 0)
__global__ __launch_bounds__(256) void prologue_coop(
    const int* __restrict__ src, const int* __restrict__ dst,
    const float* __restrict__ ts, const int* __restrict__ gt_p,
    const float* __restrict__ x, const float* __restrict__ W_t, const float* __restrict__ W_r,
    float* __restrict__ w, unsigned long long* __restrict__ pc,
    int* __restrict__ bsum, int* __restrict__ bbase,
    int* __restrict__ offs, int* __restrict__ cursor, float* __restrict__ dinv,
    unsigned* __restrict__ cv,
    unsigned short* __restrict__ xb, unsigned short* __restrict__ wtb, unsigned short* __restrict__ wrb,
    int E, int N, int nb, int n8x, int n8w) {
  cg::grid_group grid = cg::this_grid();
  __shared__ int sm[256];
  int tid = blockIdx.x * blockDim.x + threadIdx.x;
  int stride = gridDim.x * blockDim.x;
  int totE = E + N;
  float gtf = (float)(*gt_p);

  // ---- Phase A: edge weights + degree atomics, co-scheduled with bf16 casts
  for (int e = tid; e < totE; e += stride) {
    int d; float t;
    if (e < E) { d = dst[e]; t = ts[e]; }
    else       { d = e - E;  t = gtf; }
    float wv = expf(TDK * (t - gtf));
    w[e] = wv;
    unsigned long long pk = (1ULL << 52) + (unsigned long long)(wv * 4294967296.0f);
    atomicAdd(&pc[d], pk);
  }
  int n8tot = n8x + 2 * n8w;
  for (int i = tid; i < n8tot; i += stride) {
    const float* sp; unsigned short* dp; int k;
    if (i < n8x)            { sp = x;   dp = xb;  k = i; }
    else if (i < n8x + n8w) { sp = W_t; dp = wtb; k = i - n8x; }
    else                    { sp = W_r; dp = wrb; k = i - n8x - n8w; }
    const float4 v0 = *(const float4*)(sp + (size_t)k * 8);
    const float4 v1 = *(const float4*)(sp + (size_t)k * 8 + 4);
    ushort8 o;
    o[0] = f2bf(v0.x); o[1] = f2bf(v0.y); o[2] = f2bf(v0.z); o[3] = f2bf(v0.w);
    o[4] = f2bf(v1.x); o[5] = f2bf(v1.y); o[6] = f2bf(v1.z); o[7] = f2bf(v1.w);
    *(ushort8*)(dp + (size_t)k * 8) = o;
  }
  __threadfence();
  grid.sync();

  // ---- Phase B: per-segment reduce of padded counts (nb <= gridDim.x)
  for (int vb = blockIdx.x; vb < nb; vb += gridDim.x) {
    int i = vb * 256 + threadIdx.x;
    int v = (i < N) ? (((int)(pc[i] >> 52) + 3) & ~3) : 0;
    for (int o = 32; o; o >>= 1) v += __shfl_down(v, o);
    if ((threadIdx.x & 63) == 0) sm[threadIdx.x >> 6] = v;
    __syncthreads();
    if (threadIdx.x == 0) bsum[vb] = sm[0] + sm[1] + sm[2] + sm[3];
    __syncthreads();
  }
  __threadfence();
  grid.sync();

  // ---- Phase C: scan of block sums (single 256-thread block)
  if (blockIdx.x == 0) {
    int t = threadIdx.x;
    int v = (t < nb) ? bsum[t] : 0;
    sm[t] = v;
    __syncthreads();
    for (int o = 1; o < 256; o <<= 1) {
      int u = (t >= o) ? sm[t - o] : 0;
      __syncthreads();
      sm[t] += u;
      __syncthreads();
    }
    if (t < nb) bbase[t] = sm[t] - v;      // exclusive
    if (t == nb - 1) offs[N] = sm[t];      // total padded edges
  }
  __threadfence();
  grid.sync();

  // ---- Phase D: per-segment scan -> offs/cursor + dinv unpack
  for (int vb = blockIdx.x; vb < nb; vb += gridDim.x) {
    int i = vb * 256 + threadIdx.x;
    unsigned long long p = (i < N) ? pc[i] : 0ULL;
    int v = ((int)(p >> 52) + 3) & ~3;     // padded count
    sm[threadIdx.x] = v;
    __syncthreads();
    for (int o = 1; o < 256; o <<= 1) {
      int u = (threadIdx.x >= o) ? sm[threadIdx.x - o] : 0;
      __syncthreads();
      sm[threadIdx.x] += u;
      __syncthreads();
    }
    int excl = sm[threadIdx.x] - v + bbase[vb];
    if (i < N) {
      offs[i] = excl; cursor[i] = excl;
      float deg = (float)(p & ((1ULL << 52) - 1ULL)) * (1.0f / 4294967296.0f);
      dinv[i] = (deg > 0.f) ? rsqrtf(deg) : 0.f;
    }
    __syncthreads();
  }
  __threadfence();
  grid.sync();

  // ---- Phase E: scatter edges into CSR (lo16 = src, hi16 = fp16 value)
  for (int e = tid; e < totE; e += stride) {
    int s, d;
    if (e < E) { s = src[e]; d = dst[e]; }
    else       { s = d = e - E; }
    int pos = atomicAdd(&cursor[d], 1);
    float v = dinv[s] * w[e] * dinv[d];
    unsigned short hv = __half_as_ushort(__float2half(v));
    cv[pos] = (unsigned)s | ((unsigned)hv << 16);
  }
}

// ============ COOPERATIVE 5-STEP DIFFUSION: 5 kernels -> 1 launch ============
// Inner body is the FROZEN r10 spmm (r1 structure + pad-to-4 tail): one row per
// 8-lane group, 8-deep gather batch + one 4-batch, ~40 VGPR. grid.sync() +
// threadfence between steps replaces 4 kernel boundaries. Column slabs are
// XCD-private across steps (chunk c is written AND read only by chunk-c
// blocks), so no cross-XCD coherence dependence beyond the fence.
// 1024 blocks = 4/CU (co-resident up to 128 VGPR -> coop launch safe);
// 128 blocks/chunk x ~4.9 tiles each.
// Do NOT: shfl-broadcast cv (r2: +70%), nt cv (r2), two rows/group (r3: +38%),
// 16-deep batch (r6: +8%), cv-prefetch loop (r7: +3%), row-per-wave (r9: 2x).
__device__ __forceinline__ void acc8(uintx4 u, float v, float* a) {
  a[0] += v * __uint_as_float(u[0] << 16);
  a[1] += v * __uint_as_float(u[0] & 0xffff0000u);
  a[2] += v * __uint_as_float(u[1] << 16);
  a[3] += v * __uint_as_float(u[1] & 0xffff0000u);
  a[4] += v * __uint_as_float(u[2] << 16);
  a[5] += v * __uint_as_float(u[2] & 0xffff0000u);
  a[6] += v * __uint_as_float(u[3] << 16);
  a[7] += v * __uint_as_float(u[3] & 0xffff0000u);
}

__device__ __forceinline__ float cvval(unsigned cu) {
  return __half2float(__ushort_as_half((unsigned short)(cu >> 16)));
}

__global__ __launch_bounds__(256) void spmm_coop(const int* __restrict__ offs, const unsigned* __restrict__ cv,
                                                 const unsigned short* __restrict__ xb,
                                                 unsigned short* __restrict__ hba, unsigned short* __restrict__ hbb,
                                                 int N, int ntiles) {
  cg::grid_group grid = cg::this_grid();
  int chunk = blockIdx.x & 7;
  int bid8  = blockIdx.x >> 3;
  int nbpc  = gridDim.x >> 3;
  int fo = chunk * 64 + (threadIdx.x & 7) * 8;   // 8 bf16 = 16 B per lane
  int rl = threadIdx.x >> 3;                     // row within tile (0..31)

  for (int step = 0; step < 5; ++step) {
    const unsigned short* h_in = (step == 0) ? xb : ((step & 1) ? hba : hbb);
    unsigned short* h_out = (step & 1) ? hbb : hba;
    const unsigned short* hp = h_in + fo;

    for (int tile = bid8; tile < ntiles; tile += nbpc) {
      int row = tile * 32 + rl;
      if (row < N) {
        int s = offs[row], e = offs[row + 1];
        float a[8] = {0.f, 0.f, 0.f, 0.f, 0.f, 0.f, 0.f, 0.f};
        int j = s;
        for (; j + 8 <= e; j += 8) {
          unsigned cu[8]; uintx4 u[8];
#pragma unroll
          for (int t = 0; t < 8; ++t) cu[t] = cv[j + t];
#pragma unroll
          for (int t = 0; t < 8; ++t) u[t] = *(const uintx4*)(hp + ((cu[t] & 0xffffu) << 9));
#pragma unroll
          for (int t = 0; t < 8; ++t) acc8(u[t], cvval(cu[t]), a);
        }
        if (j < e) {                      // padded: exactly 4 edges remain
          unsigned cu[4]; uintx4 u[4];
#pragma unroll
          for (int t = 0; t < 4; ++t) cu[t] = cv[j + t];
#pragma unroll
          for (int t = 0; t < 4; ++t) u[t] = *(const uintx4*)(hp + ((cu[t] & 0xffffu) << 9));
#pragma unroll
          for (int t = 0; t < 4; ++t) acc8(u[t], cvval(cu[t]), a);
        }
        // self term: h + dt*(Ah - h)
        uintx4 ud = *(const uintx4*)(hp + (row << 9));
        float hd[8];
        hd[0] = __uint_as_float(ud[0] << 16); hd[1] = __uint_as_float(ud[0] & 0xffff0000u);
        hd[2] = __uint_as_float(ud[1] << 16); hd[3] = __uint_as_float(ud[1] & 0xffff0000u);
        hd[4] = __uint_as_float(ud[2] << 16); hd[5] = __uint_as_float(ud[2] & 0xffff0000u);
        hd[6] = __uint_as_float(ud[3] << 16); hd[7] = __uint_as_float(ud[3] & 0xffff0000u);
        uintx4 o;
        unsigned int p0, p1;
#define PACK(k0, k1, dst_)                                        \
        { float o0 = hd[k0] + DTs * (a[k0] - hd[k0]);             \
          float o1 = hd[k1] + DTs * (a[k1] - hd[k1]);             \
          p0 = f2bf(o0); p1 = f2bf(o1); dst_ = p0 | (p1 << 16); }
        PACK(0, 1, o[0]) PACK(2, 3, o[1]) PACK(4, 5, o[2]) PACK(6, 7, o[3])
#undef PACK
        __builtin_nontemporal_store(o, (uintx4*)(h_out + (size_t)row * FDIM + fo));
      }
    }
    if (step < 4) {
      __threadfence();
      grid.sync();
    }
  }
}

// --- fused dual GEMM, SEQUENTIAL two-phase, double-buffered async-LDS --------
// out = relu(Ah @ Wt^T + bias) + Ax @ Wr^T
// r1 configuration -- measured best of this structure (40.3 us): tile 128x128,
// BK=32, 4 waves 2x2, LDS 32 KB, grid 628 + bijective XCD swizzle. Knob record:
// 64x128 = 42.6 (r4), BK=64/48KB = 48.3 (r5). 2-barrier vmcnt(0) loop plateaus
// ~40 us (m97-structure ceiling); N=512 too narrow for 8-phase 256^2. FROZEN.
__global__ __launch_bounds__(256, 3) void gemm_fused(const __bf16* __restrict__ Ah, const __bf16* __restrict__ Ax,
                                                     const __bf16* __restrict__ Wt, const __bf16* __restrict__ Wr,
                                                     const float* __restrict__ bias, float* __restrict__ out,
                                                     int M, int NB) {
  __shared__ __bf16 sA[2][128 * 32];
  __shared__ __bf16 sB[2][128 * 32];
  int tid = threadIdx.x;
  int wid = tid >> 6, lane = tid & 63;
  int wm = wid & 1, wn = wid >> 1;
  int lane15 = lane & 15, quad = lane >> 4;

  // bijective XCD swizzle (works for NB % 8 != 0): d%8 = XCD, d/8 = slot;
  // XCD x covers g in a contiguous range -> mi runs contiguous, ni = g&3.
  int d = blockIdx.x;
  int x = d & 7, s = d >> 3;
  int q = NB >> 3, r = NB & 7;
  int g = (x < r ? x * (q + 1) : r * (q + 1) + (x - r) * q) + s;
  int mi = g >> 2, ni = g & 3;
  int m0 = mi * 128, n0 = ni * 128;

  // staging: wave covers rows [wid*32, wid*32+32), 2 instrs of 16 rows each.
  // lane -> row wid*32 + lane/4 (+16), swizzled k-segment ((lane&3)-(lane>>3))&3
  int r0 = wid * 32 + (lane >> 2);
  int c0 = ((((lane & 3) - (lane >> 3)) & 3)) * 8;   // swizzled element offset
  int am0 = m0 + r0;      if (am0 >= M) am0 = M - 1;
  int am1 = m0 + r0 + 16; if (am1 >= M) am1 = M - 1;
  int bn0 = n0 + r0;                                 // N dim = 512, full tiles
  const __bf16* a00 = Ah + (size_t)am0 * FDIM + c0;  // phase-1 A
  const __bf16* a01 = Ah + (size_t)am1 * FDIM + c0;
  const __bf16* a10 = Ax + (size_t)am0 * FDIM + c0;  // phase-2 A
  const __bf16* a11 = Ax + (size_t)am1 * FDIM + c0;
  const __bf16* b00 = Wt + (size_t)bn0 * FDIM + c0;  // phase-1 B
  const __bf16* b01 = Wt + (size_t)(bn0 + 16) * FDIM + c0;
  const __bf16* b10 = Wr + (size_t)bn0 * FDIM + c0;  // phase-2 B
  const __bf16* b11 = Wr + (size_t)(bn0 + 16) * FDIM + c0;
  int loff0 = wid * 1024;          // (wid*32 rows) * 32 elems
  int loff1 = wid * 1024 + 512;    // +16 rows

  auto stage = [&](int b, const __bf16* pa0, const __bf16* pa1,
                   const __bf16* pb0, const __bf16* pb1, int kt) {
    gld16(pa0 + kt, &sA[b][loff0]); gld16(pa1 + kt, &sA[b][loff1]);
    gld16(pb0 + kt, &sB[b][loff0]); gld16(pb1 + kt, &sB[b][loff1]);
  };

  // read-side swizzled k offset: slot = (quad + (row>>1)) & 3
  int koff = ((quad + (lane15 >> 1)) & 3) * 8;

  // bias for this wave's 4 n-fragments (needed at the phase transition)
  float bn[4];
#pragma unroll
  for (int in = 0; in < 4; ++in) bn[in] = bias[n0 + wn * 64 + in * 16 + lane15];

  floatx4 acc[4][4];
  floatx4 z4; z4[0] = 0.f; z4[1] = 0.f; z4[2] = 0.f; z4[3] = 0.f;
#pragma unroll
  for (int im = 0; im < 4; ++im)
#pragma unroll
    for (int in = 0; in < 4; ++in) acc[im][in] = z4;

  stage(0, a00, a01, b00, b01, 0);
  for (int it = 0; it < 32; ++it) {
    int cb = it & 1;
    __syncthreads();                       // staging of buf cb complete; prior reads of buf 1-cb done
    int nx = it + 1;
    if (nx < 32) {
      if (nx < 16) stage(1 - cb, a00, a01, b00, b01, nx * 32);
      else         stage(1 - cb, a10, a11, b10, b11, (nx & 15) * 32);
    }
    if (it == 16) {                        // phase transition: relu(acc + bias), in registers
#pragma unroll
      for (int im = 0; im < 4; ++im)
#pragma unroll
        for (int in = 0; in < 4; ++in)
#pragma unroll
          for (int rr = 0; rr < 4; ++rr)
            acc[im][in][rr] = fmaxf(acc[im][in][rr] + bn[in], 0.f);
    }
    bf16x8 af[4], br[4];
#pragma unroll
    for (int im = 0; im < 4; ++im)
      af[im] = *(const bf16x8*)(&sA[cb][(wm * 64 + im * 16 + lane15) * 32 + koff]);
#pragma unroll
    for (int in = 0; in < 4; ++in)
      br[in] = *(const bf16x8*)(&sB[cb][(wn * 64 + in * 16 + lane15) * 32 + koff]);
#pragma unroll
    for (int im = 0; im < 4; ++im)
#pragma unroll
      for (int in = 0; in < 4; ++in)
        acc[im][in] = __builtin_amdgcn_mfma_f32_16x16x32_bf16(af[im], br[in], acc[im][in], 0, 0, 0);
  }

  // epilogue: C/D layout col=lane&15, row=quad*4+reg
#pragma unroll
  for (int im = 0; im < 4; ++im) {
#pragma unroll
    for (int in = 0; in < 4; ++in) {
#pragma unroll
      for (int rr = 0; rr < 4; ++rr) {
        int m = m0 + wm * 64 + im * 16 + quad * 4 + rr;
        int n = n0 + wn * 64 + in * 16 + lane15;
        if (m < M) out[(size_t)m * FDIM + n] = acc[im][in][rr];
      }
    }
  }
}

// ------------------------------ rowwise LayerNorm -----------------------------
__global__ __launch_bounds__(256) void ln_kernel(const float* __restrict__ pre, const float* __restrict__ gamma,
                                                 const float* __restrict__ beta, float* __restrict__ out) {
  int row = blockIdx.x, t = threadIdx.x;
  float2 v = *(const float2*)(pre + (size_t)row * FDIM + t * 2);
  float s = v.x + v.y;
  float ss = v.x * v.x + v.y * v.y;
  for (int off = 32; off; off >>= 1) { s += __shfl_down(s, off); ss += __shfl_down(ss, off); }
  __shared__ float sm[4], sm2[4];
  int wid = t >> 6, lane = t & 63;
  if (lane == 0) { sm[wid] = s; sm2[wid] = ss; }
  __syncthreads();
  if (t == 0) {
    float a = sm[0] + sm[1] + sm[2] + sm[3];
    float b = sm2[0] + sm2[1] + sm2[2] + sm2[3];
    sm[0] = a; sm2[0] = b;
  }
  __syncthreads();
  float mu = sm[0] * (1.f / FDIM);
  float var = sm2[0] * (1.f / FDIM) - mu * mu;
  float inv = rsqrtf(var + EPSv);
  float2 g  = *(const float2*)(gamma + t * 2);
  float2 bb = *(const float2*)(beta + t * 2);
  float2 o;
  o.x = (v.x - mu) * inv * g.x + bb.x;
  o.y = (v.y - mu) * inv * g.y + bb.y;
  *(float2*)(out + (size_t)row * FDIM + t * 2) = o;
}

extern "C" void kernel_launch(void* const* d_in, const int* in_sizes, int n_in,
                              void* d_out, int out_size, void* d_ws, size_t ws_size,
                              hipStream_t stream) {
  const float* x     = (const float*)d_in[0];
  const int*   ei    = (const int*)d_in[1];
  const float* ts    = (const float*)d_in[2];
  const float* W_t   = (const float*)d_in[3];
  const float* b_t   = (const float*)d_in[4];
  const float* W_r   = (const float*)d_in[5];
  const float* gamma = (const float*)d_in[6];
  const float* beta  = (const float*)d_in[7];
  const int*   gt    = (const int*)d_in[8];

  int E = in_sizes[2];
  int N = in_sizes[0] / FDIM;
  const int* src = ei;
  const int* dst = ei + E;
  const int totE = E + N;
  const int totEp = totE + 3 * N;   // upper bound on padded edge count
  int nb = (N + 255) / 256;         // scan segments (N=20000 -> 79 <= 256)

  // ---- workspace carve (all regions fully rewritten every call) ----
  char* base = (char*)d_ws;
  size_t off = 0;
  auto carve = [&](size_t bytes) -> char* {
    char* r = base + off;
    off = (off + bytes + 255) & ~(size_t)255;
    return r;
  };
  unsigned long long* pc = (unsigned long long*)carve((size_t)N * 8);   // packed cnt|deg
  unsigned* cv = (unsigned*)carve((size_t)totEp * 4);                    // CSR payload (pad slots stay 0)
  size_t zero_bytes = off;                       // pc + cv zeroed (cv=0 pad edge: src 0, val 0)
  float* dinv  = (float*)carve((size_t)N * 4);
  int*   offs  = (int*)  carve((size_t)(N + 1) * 4);
  int*   cursor= (int*)  carve((size_t)N * 4);
  int*   bsum  = (int*)  carve((size_t)nb * 4);
  int*   bbase = (int*)  carve((size_t)nb * 4);
  float* w     = (float*)carve((size_t)totE * 4);
  unsigned short* xb  = (unsigned short*)carve((size_t)N * FDIM * 2);   // bf16(x)
  unsigned short* hba = (unsigned short*)carve((size_t)N * FDIM * 2);   // bf16 h ping
  unsigned short* hbb = (unsigned short*)carve((size_t)N * FDIM * 2);   // bf16 h pong
  unsigned short* wtb = (unsigned short*)carve((size_t)FDIM * FDIM * 2);
  unsigned short* wrb = (unsigned short*)carve((size_t)FDIM * FDIM * 2);
  float* preLN = (float*)carve((size_t)N * FDIM * 4);

  hipMemsetAsync(d_ws, 0, zero_bytes, stream);

  int n8x = N * FDIM / 8;
  int n8w = FDIM * FDIM / 8;

  // 1 cooperative launch replaces 6 prologue/cast kernels
  {
    void* args[] = {(void*)&src, (void*)&dst, (void*)&ts, (void*)&gt,
                    (void*)&x, (void*)&W_t, (void*)&W_r,
                    (void*)&w, (void*)&pc, (void*)&bsum, (void*)&bbase,
                    (void*)&offs, (void*)&cursor, (void*)&dinv, (void*)&cv,
                    (void*)&xb, (void*)&wtb, (void*)&wrb,
                    (void*)&E, (void*)&N, (void*)&nb, (void*)&n8x, (void*)&n8w};
    hipLaunchCooperativeKernel((const void*)prologue_coop, dim3(1024), dim3(256), args, 0, stream);
  }

  // 1 cooperative launch replaces the 5 diffusion-step kernels
  {
    int ntiles = (N + 31) / 32;
    void* args[] = {(void*)&offs, (void*)&cv, (void*)&xb, (void*)&hba, (void*)&hbb,
                    (void*)&N, (void*)&ntiles};
    hipLaunchCooperativeKernel((const void*)spmm_coop, dim3(1024), dim3(256), args, 0, stream);
  }

  // fused: preLN = relu(h @ Wt^T + b_t) + x @ Wr^T  (5 steps end in hba)
  int MB = (N + 127) / 128;
  int NBLK = MB * (FDIM / 128);
  gemm_fused<<<NBLK, 256, 0, stream>>>((const __bf16*)hba, (const __bf16*)xb,
                                       (const __bf16*)wtb, (const __bf16*)wrb,
                                       b_t, preLN, N, NBLK);

  ln_kernel<<<N, 256, 0, stream>>>(preLN, gamma, beta, (float*)d_out);
}

// Round 12
// 339.463 us; speedup vs baseline: 5.8934x; 5.8934x over previous
//
#include <hip/hip_runtime.h>
#include <hip/hip_fp16.h>

// Problem constants (from reference)
#define FDIM 512
#define TDK  0.1f   // TIME_DECAY
#define DTs  0.2f   // DIFF_T / NUM_STEPS
#define EPSv 1e-5f

using bf16x8  = __attribute__((ext_vector_type(8))) __bf16;
using floatx4 = __attribute__((ext_vector_type(4))) float;
using ushort8 = __attribute__((ext_vector_type(8))) unsigned short;
using uintx4  = __attribute__((ext_vector_type(4))) unsigned int;   // native vec for nontemporal builtins

__device__ __forceinline__ unsigned short f2bf(float f) {
  unsigned int u = __float_as_uint(f);
  u += 0x7fffu + ((u >> 16) & 1u);   // RNE
  return (unsigned short)(u >> 16);
}

// async global->LDS, 16 B per lane; LDS dest = wave-uniform base + lane*16
__device__ __forceinline__ void gld16(const __bf16* g, __bf16* l) {
  __builtin_amdgcn_global_load_lds(
      (const __attribute__((address_space(1))) unsigned int*)g,
      (__attribute__((address_space(3))) unsigned int*)l, 16, 0, 0);
}

// ==== prep: edge weights + degree atomic + slot index + all bf16 casts =======
// ONE launch (was 2). NO grid.sync anywhere (r11 lesson: grid-wide sync forces
// cross-XCD L2 coherence -> flushes the per-XCD L2s, 6x slowdown; cooperative
// fusion is dead). The two grid-stride loops are independent: atomic-latency
// edge pass overlaps the streaming casts.
// ts.max() eliminated algebraically (w = exp(TDK*(t-gt)) cancels in ew).
// Packed 64-bit atomic: bits52+ = count, bits0..51 = fixed-point deg (w*2^32).
// The atomic RETURN VALUE's count field = this edge's slot within its dst row
// -> stored in pos16 so scatter needs NO atomics at all.
__global__ __launch_bounds__(256) void prep_kernel(
    const int* __restrict__ src, const int* __restrict__ dst,
    const float* __restrict__ ts, const int* __restrict__ gt_p,
    const float* __restrict__ x, const float* __restrict__ W_t, const float* __restrict__ W_r,
    float* __restrict__ w, unsigned short* __restrict__ pos16,
    unsigned long long* __restrict__ pc,
    unsigned short* __restrict__ xb, unsigned short* __restrict__ wtb, unsigned short* __restrict__ wrb,
    int E, int N, int n8x, int n8w) {
  int tid = blockIdx.x * blockDim.x + threadIdx.x;
  int stride = gridDim.x * blockDim.x;
  int totE = E + N;
  float gtf = (float)(*gt_p);
  for (int e = tid; e < totE; e += stride) {
    int d; float t;
    if (e < E) { d = dst[e]; t = ts[e]; }
    else       { d = e - E;  t = gtf; }
    float wv = expf(TDK * (t - gtf));
    w[e] = wv;
    unsigned long long pk = (1ULL << 52) + (unsigned long long)(wv * 4294967296.0f);
    unsigned long long old = atomicAdd(&pc[d], pk);
    pos16[e] = (unsigned short)(old >> 52);     // slot within dst row
  }
  int n8tot = n8x + 2 * n8w;
  for (int i = tid; i < n8tot; i += stride) {
    const float* sp; unsigned short* dp; int k;
    if (i < n8x)            { sp = x;   dp = xb;  k = i; }
    else if (i < n8x + n8w) { sp = W_t; dp = wtb; k = i - n8x; }
    else                    { sp = W_r; dp = wrb; k = i - n8x - n8w; }
    const float4 v0 = *(const float4*)(sp + (size_t)k * 8);
    const float4 v1 = *(const float4*)(sp + (size_t)k * 8 + 4);
    ushort8 o;
    o[0] = f2bf(v0.x); o[1] = f2bf(v0.y); o[2] = f2bf(v0.z); o[3] = f2bf(v0.w);
    o[4] = f2bf(v1.x); o[5] = f2bf(v1.y); o[6] = f2bf(v1.z); o[7] = f2bf(v1.w);
    *(ushort8*)(dp + (size_t)k * 8) = o;
  }
}

// ==== single-pass scan over PADDED counts via aggregate-lookback =============
// Replaces seg_reduce + scan_bsum + seg_scan (3 launches -> 1). Each of the
// nb (=79) blocks scans its 256 counts, publishes its total with ONE
// device-scope atomicExch (total >= 1024 because every row has a self-loop and
// counts are padded to x4 -> 0 means "unpublished", no separate flag), then
// polls predecessors' aggregates with atomic loads. All 79 blocks co-resident
// (79 << capacity) -> no deadlock; no dispatch-order assumption.
// Counts padded to x4: pad cv slots stay zero (src 0, weight fp16(0) -> 0),
// so the spmm loop needs no serial tail.
__global__ __launch_bounds__(256) void scan_lookback(
    const unsigned long long* __restrict__ pc, int* __restrict__ agg,
    int* __restrict__ offs, float* __restrict__ dinv, int N, int nb) {
  __shared__ int sm[256];
  __shared__ int wsum[4];
  int b = blockIdx.x, t = threadIdx.x;
  int i = b * 256 + t;
  unsigned long long p = (i < N) ? pc[i] : 0ULL;
  int v = ((int)(p >> 52) + 3) & ~3;              // padded count
  sm[t] = v;
  __syncthreads();
  for (int o = 1; o < 256; o <<= 1) {
    int u = (t >= o) ? sm[t - o] : 0;
    __syncthreads();
    sm[t] += u;
    __syncthreads();
  }
  int total = sm[255];
  if (t == 0) atomicExch(&agg[b], total);         // publish (device-scope)
  int part = 0;
  for (int k = t; k < b; k += 256) {              // b <= 78 < 256: <=1 iter
    int a;
    do { a = atomicAdd(&agg[k], 0); } while (a == 0);
    part += a;
  }
  for (int o = 32; o; o >>= 1) part += __shfl_down(part, o);
  if ((t & 63) == 0) wsum[t >> 6] = part;
  __syncthreads();
  int base = wsum[0] + wsum[1] + wsum[2] + wsum[3];
  int excl = base + sm[t] - v;
  if (i < N) {
    offs[i] = excl;
    float deg = (float)(p & ((1ULL << 52) - 1ULL)) * (1.0f / 4294967296.0f);
    dinv[i] = (deg > 0.f) ? rsqrtf(deg) : 0.f;
  }
  if (b == nb - 1 && t == 255) offs[N] = base + total;
}

// -- scatter edges into CSR, NO atomics: slot = offs[dst] + pos16[e] ----------
// packed 4 B: lo16 = src (N<65536), hi16 = fp16 value
__global__ __launch_bounds__(256) void scatter_kernel(const int* __restrict__ src, const int* __restrict__ dst,
                                                      const float* __restrict__ w, const unsigned short* __restrict__ pos16,
                                                      const float* __restrict__ dinv, const int* __restrict__ offs,
                                                      unsigned* __restrict__ cv, int E, int N) {
  int e = blockIdx.x * blockDim.x + threadIdx.x;
  if (e >= E + N) return;
  int s, d;
  if (e < E) { s = src[e]; d = dst[e]; }
  else       { s = d = e - E; }
  int pos = offs[d] + (int)pos16[e];
  float v = dinv[s] * w[e] * dinv[d];
  unsigned short hv = __half_as_ushort(__float2half(v));
  cv[pos] = (unsigned)s | ((unsigned)hv << 16);
}

// ---- one diffusion step, bf16 state, XCD-AFFINE feature chunks --------------
// FROZEN r10 structure (measured best; survived 6 structural attacks): one row
// per 8-lane group, 32 rows/block, grid 5008, 8-deep gather batch + one
// 4-batch (pad-to-4, no serial tail), ~40 VGPR -> 8 waves/SIMD.
// Do NOT: shfl-broadcast cv (r2: +70%), nt cv (r2), two rows/group (r3: +38%),
// 16-deep batch (r6: +8%), cv-prefetch loop (r7: +3%), row-per-wave (r9: 2x),
// cooperative 5-in-1 with grid.sync (r11: 6x -- L2 flush).
// chunk = blockIdx.x & 7 -> all of chunk c on one XCD; 2.56 MB slab L2-resident
// (FETCH ~= compulsory confirms). h_out nontemporal so writes don't evict slab.
__device__ __forceinline__ void acc8(uintx4 u, float v, float* a) {
  a[0] += v * __uint_as_float(u[0] << 16);
  a[1] += v * __uint_as_float(u[0] & 0xffff0000u);
  a[2] += v * __uint_as_float(u[1] << 16);
  a[3] += v * __uint_as_float(u[1] & 0xffff0000u);
  a[4] += v * __uint_as_float(u[2] << 16);
  a[5] += v * __uint_as_float(u[2] & 0xffff0000u);
  a[6] += v * __uint_as_float(u[3] << 16);
  a[7] += v * __uint_as_float(u[3] & 0xffff0000u);
}

__device__ __forceinline__ float cvval(unsigned cu) {
  return __half2float(__ushort_as_half((unsigned short)(cu >> 16)));
}

__global__ __launch_bounds__(256) void spmm_xcd(const int* __restrict__ offs, const unsigned* __restrict__ cv,
                                                const unsigned short* __restrict__ h_in,
                                                unsigned short* __restrict__ h_out, int N) {
  int chunk = blockIdx.x & 7;
  int tile  = blockIdx.x >> 3;
  int row = tile * 32 + (threadIdx.x >> 3);
  if (row >= N) return;
  int fo = chunk * 64 + (threadIdx.x & 7) * 8;   // 8 bf16 = 16 B per lane
  const unsigned short* hp = h_in + fo;
  int s = offs[row], e = offs[row + 1];
  float a[8] = {0.f, 0.f, 0.f, 0.f, 0.f, 0.f, 0.f, 0.f};
  int j = s;
  for (; j + 8 <= e; j += 8) {
    unsigned cu[8]; uintx4 u[8];
#pragma unroll
    for (int t = 0; t < 8; ++t) cu[t] = cv[j + t];
#pragma unroll
    for (int t = 0; t < 8; ++t) u[t] = *(const uintx4*)(hp + ((cu[t] & 0xffffu) << 9));
#pragma unroll
    for (int t = 0; t < 8; ++t) acc8(u[t], cvval(cu[t]), a);
  }
  if (j < e) {                          // padded: exactly 4 edges remain
    unsigned cu[4]; uintx4 u[4];
#pragma unroll
    for (int t = 0; t < 4; ++t) cu[t] = cv[j + t];
#pragma unroll
    for (int t = 0; t < 4; ++t) u[t] = *(const uintx4*)(hp + ((cu[t] & 0xffffu) << 9));
#pragma unroll
    for (int t = 0; t < 4; ++t) acc8(u[t], cvval(cu[t]), a);
  }
  // self term: h + dt*(Ah - h)
  uintx4 ud = *(const uintx4*)(hp + (row << 9));
  float hd[8];
  hd[0] = __uint_as_float(ud[0] << 16); hd[1] = __uint_as_float(ud[0] & 0xffff0000u);
  hd[2] = __uint_as_float(ud[1] << 16); hd[3] = __uint_as_float(ud[1] & 0xffff0000u);
  hd[4] = __uint_as_float(ud[2] << 16); hd[5] = __uint_as_float(ud[2] & 0xffff0000u);
  hd[6] = __uint_as_float(ud[3] << 16); hd[7] = __uint_as_float(ud[3] & 0xffff0000u);
  uintx4 o;
  unsigned int p0, p1;
#define PACK(k0, k1, dst_)                                        \
  { float o0 = hd[k0] + DTs * (a[k0] - hd[k0]);                   \
    float o1 = hd[k1] + DTs * (a[k1] - hd[k1]);                   \
    p0 = f2bf(o0); p1 = f2bf(o1); dst_ = p0 | (p1 << 16); }
  PACK(0, 1, o[0]) PACK(2, 3, o[1]) PACK(4, 5, o[2]) PACK(6, 7, o[3])
#undef PACK
  __builtin_nontemporal_store(o, (uintx4*)(h_out + (size_t)row * FDIM + fo));
}

// --- fused dual GEMM, SEQUENTIAL two-phase, double-buffered async-LDS --------
// out = relu(Ah @ Wt^T + bias) + Ax @ Wr^T
// r1 configuration -- measured best of this structure (40.3 us): tile 128x128,
// BK=32, 4 waves 2x2, LDS 32 KB, grid 628 + bijective XCD swizzle. Knob record:
// 64x128 = 42.6 (r4), BK=64/48KB = 48.3 (r5). 2-barrier vmcnt(0) loop plateaus
// ~40 us (m97-structure ceiling); N=512 too narrow for 8-phase 256^2. FROZEN.
__global__ __launch_bounds__(256, 3) void gemm_fused(const __bf16* __restrict__ Ah, const __bf16* __restrict__ Ax,
                                                     const __bf16* __restrict__ Wt, const __bf16* __restrict__ Wr,
                                                     const float* __restrict__ bias, float* __restrict__ out,
                                                     int M, int NB) {
  __shared__ __bf16 sA[2][128 * 32];
  __shared__ __bf16 sB[2][128 * 32];
  int tid = threadIdx.x;
  int wid = tid >> 6, lane = tid & 63;
  int wm = wid & 1, wn = wid >> 1;
  int lane15 = lane & 15, quad = lane >> 4;

  // bijective XCD swizzle (works for NB % 8 != 0): d%8 = XCD, d/8 = slot;
  // XCD x covers g in a contiguous range -> mi runs contiguous, ni = g&3.
  int d = blockIdx.x;
  int x = d & 7, s = d >> 3;
  int q = NB >> 3, r = NB & 7;
  int g = (x < r ? x * (q + 1) : r * (q + 1) + (x - r) * q) + s;
  int mi = g >> 2, ni = g & 3;
  int m0 = mi * 128, n0 = ni * 128;

  // staging: wave covers rows [wid*32, wid*32+32), 2 instrs of 16 rows each.
  // lane -> row wid*32 + lane/4 (+16), swizzled k-segment ((lane&3)-(lane>>3))&3
  int r0 = wid * 32 + (lane >> 2);
  int c0 = ((((lane & 3) - (lane >> 3)) & 3)) * 8;   // swizzled element offset
  int am0 = m0 + r0;      if (am0 >= M) am0 = M - 1;
  int am1 = m0 + r0 + 16; if (am1 >= M) am1 = M - 1;
  int bn0 = n0 + r0;                                 // N dim = 512, full tiles
  const __bf16* a00 = Ah + (size_t)am0 * FDIM + c0;  // phase-1 A
  const __bf16* a01 = Ah + (size_t)am1 * FDIM + c0;
  const __bf16* a10 = Ax + (size_t)am0 * FDIM + c0;  // phase-2 A
  const __bf16* a11 = Ax + (size_t)am1 * FDIM + c0;
  const __bf16* b00 = Wt + (size_t)bn0 * FDIM + c0;  // phase-1 B
  const __bf16* b01 = Wt + (size_t)(bn0 + 16) * FDIM + c0;
  const __bf16* b10 = Wr + (size_t)bn0 * FDIM + c0;  // phase-2 B
  const __bf16* b11 = Wr + (size_t)(bn0 + 16) * FDIM + c0;
  int loff0 = wid * 1024;          // (wid*32 rows) * 32 elems
  int loff1 = wid * 1024 + 512;    // +16 rows

  auto stage = [&](int b, const __bf16* pa0, const __bf16* pa1,
                   const __bf16* pb0, const __bf16* pb1, int kt) {
    gld16(pa0 + kt, &sA[b][loff0]); gld16(pa1 + kt, &sA[b][loff1]);
    gld16(pb0 + kt, &sB[b][loff0]); gld16(pb1 + kt, &sB[b][loff1]);
  };

  // read-side swizzled k offset: slot = (quad + (row>>1)) & 3
  int koff = ((quad + (lane15 >> 1)) & 3) * 8;

  // bias for this wave's 4 n-fragments (needed at the phase transition)
  float bn[4];
#pragma unroll
  for (int in = 0; in < 4; ++in) bn[in] = bias[n0 + wn * 64 + in * 16 + lane15];

  floatx4 acc[4][4];
  floatx4 z4; z4[0] = 0.f; z4[1] = 0.f; z4[2] = 0.f; z4[3] = 0.f;
#pragma unroll
  for (int im = 0; im < 4; ++im)
#pragma unroll
    for (int in = 0; in < 4; ++in) acc[im][in] = z4;

  stage(0, a00, a01, b00, b01, 0);
  for (int it = 0; it < 32; ++it) {
    int cb = it & 1;
    __syncthreads();                       // staging of buf cb complete; prior reads of buf 1-cb done
    int nx = it + 1;
    if (nx < 32) {
      if (nx < 16) stage(1 - cb, a00, a01, b00, b01, nx * 32);
      else         stage(1 - cb, a10, a11, b10, b11, (nx & 15) * 32);
    }
    if (it == 16) {                        // phase transition: relu(acc + bias), in registers
#pragma unroll
      for (int im = 0; im < 4; ++im)
#pragma unroll
        for (int in = 0; in < 4; ++in)
#pragma unroll
          for (int rr = 0; rr < 4; ++rr)
            acc[im][in][rr] = fmaxf(acc[im][in][rr] + bn[in], 0.f);
    }
    bf16x8 af[4], br[4];
#pragma unroll
    for (int im = 0; im < 4; ++im)
      af[im] = *(const bf16x8*)(&sA[cb][(wm * 64 + im * 16 + lane15) * 32 + koff]);
#pragma unroll
    for (int in = 0; in < 4; ++in)
      br[in] = *(const bf16x8*)(&sB[cb][(wn * 64 + in * 16 + lane15) * 32 + koff]);
#pragma unroll
    for (int im = 0; im < 4; ++im)
#pragma unroll
      for (int in = 0; in < 4; ++in)
        acc[im][in] = __builtin_amdgcn_mfma_f32_16x16x32_bf16(af[im], br[in], acc[im][in], 0, 0, 0);
  }

  // epilogue: C/D layout col=lane&15, row=quad*4+reg
#pragma unroll
  for (int im = 0; im < 4; ++im) {
#pragma unroll
    for (int in = 0; in < 4; ++in) {
#pragma unroll
      for (int rr = 0; rr < 4; ++rr) {
        int m = m0 + wm * 64 + im * 16 + quad * 4 + rr;
        int n = n0 + wn * 64 + in * 16 + lane15;
        if (m < M) out[(size_t)m * FDIM + n] = acc[im][in][rr];
      }
    }
  }
}

// ------------------------------ rowwise LayerNorm -----------------------------
__global__ __launch_bounds__(256) void ln_kernel(const float* __restrict__ pre, const float* __restrict__ gamma,
                                                 const float* __restrict__ beta, float* __restrict__ out) {
  int row = blockIdx.x, t = threadIdx.x;
  float2 v = *(const float2*)(pre + (size_t)row * FDIM + t * 2);
  float s = v.x + v.y;
  float ss = v.x * v.x + v.y * v.y;
  for (int off = 32; off; off >>= 1) { s += __shfl_down(s, off); ss += __shfl_down(ss, off); }
  __shared__ float sm[4], sm2[4];
  int wid = t >> 6, lane = t & 63;
  if (lane == 0) { sm[wid] = s; sm2[wid] = ss; }
  __syncthreads();
  if (t == 0) {
    float a = sm[0] + sm[1] + sm[2] + sm[3];
    float b = sm2[0] + sm2[1] + sm2[2] + sm2[3];
    sm[0] = a; sm2[0] = b;
  }
  __syncthreads();
  float mu = sm[0] * (1.f / FDIM);
  float var = sm2[0] * (1.f / FDIM) - mu * mu;
  float inv = rsqrtf(var + EPSv);
  float2 g  = *(const float2*)(gamma + t * 2);
  float2 bb = *(const float2*)(beta + t * 2);
  float2 o;
  o.x = (v.x - mu) * inv * g.x + bb.x;
  o.y = (v.y - mu) * inv * g.y + bb.y;
  *(float2*)(out + (size_t)row * FDIM + t * 2) = o;
}

extern "C" void kernel_launch(void* const* d_in, const int* in_sizes, int n_in,
                              void* d_out, int out_size, void* d_ws, size_t ws_size,
                              hipStream_t stream) {
  const float* x     = (const float*)d_in[0];
  const int*   ei    = (const int*)d_in[1];
  const float* ts    = (const float*)d_in[2];
  const float* W_t   = (const float*)d_in[3];
  const float* b_t   = (const float*)d_in[4];
  const float* W_r   = (const float*)d_in[5];
  const float* gamma = (const float*)d_in[6];
  const float* beta  = (const float*)d_in[7];
  const int*   gt    = (const int*)d_in[8];

  const int E = in_sizes[2];
  const int N = in_sizes[0] / FDIM;
  const int* src = ei;
  const int* dst = ei + E;
  const int totE = E + N;
  const int totEp = totE + 3 * N;   // upper bound on padded edge count
  const int nb = (N + 255) / 256;   // scan segments (N=20000 -> 79 <= 256)

  // ---- workspace carve (all regions fully rewritten every call) ----
  char* base = (char*)d_ws;
  size_t off = 0;
  auto carve = [&](size_t bytes) -> char* {
    char* r = base + off;
    off = (off + bytes + 255) & ~(size_t)255;
    return r;
  };
  unsigned long long* pc = (unsigned long long*)carve((size_t)N * 8);   // packed cnt|deg
  unsigned* cv = (unsigned*)carve((size_t)totEp * 4);                    // CSR payload (pad slots stay 0)
  int* agg     = (int*)carve((size_t)nb * 4);                            // scan aggregates (0 = unpublished)
  size_t zero_bytes = off;                       // pc + cv + agg zeroed
  float* dinv  = (float*)carve((size_t)N * 4);
  int*   offs  = (int*)  carve((size_t)(N + 1) * 4);
  float* w     = (float*)carve((size_t)totE * 4);
  unsigned short* pos16 = (unsigned short*)carve((size_t)totE * 2);
  unsigned short* xb  = (unsigned short*)carve((size_t)N * FDIM * 2);   // bf16(x)
  unsigned short* hba = (unsigned short*)carve((size_t)N * FDIM * 2);   // bf16 h ping
  unsigned short* hbb = (unsigned short*)carve((size_t)N * FDIM * 2);   // bf16 h pong
  unsigned short* wtb = (unsigned short*)carve((size_t)FDIM * FDIM * 2);
  unsigned short* wrb = (unsigned short*)carve((size_t)FDIM * FDIM * 2);
  float* preLN = (float*)carve((size_t)N * FDIM * 4);

  hipMemsetAsync(d_ws, 0, zero_bytes, stream);

  int n8x = N * FDIM / 8;
  int n8w = FDIM * FDIM / 8;

  prep_kernel<<<2048, 256, 0, stream>>>(src, dst, ts, gt, x, W_t, W_r,
                                        w, pos16, pc, xb, wtb, wrb, E, N, n8x, n8w);
  scan_lookback<<<nb, 256, 0, stream>>>(pc, agg, offs, dinv, N, nb);
  scatter_kernel<<<(totE + 255) / 256, 256, 0, stream>>>(src, dst, w, pos16, dinv, offs, cv, E, N);

  // 5 Euler steps on bf16 state; chunk = blockIdx&7 -> XCD-affine L2 residency
  int sgrid = ((N + 31) / 32) * 8;
  spmm_xcd<<<sgrid, 256, 0, stream>>>(offs, cv, xb,  hba, N);
  spmm_xcd<<<sgrid, 256, 0, stream>>>(offs, cv, hba, hbb, N);
  spmm_xcd<<<sgrid, 256, 0, stream>>>(offs, cv, hbb, hba, N);
  spmm_xcd<<<sgrid, 256, 0, stream>>>(offs, cv, hba, hbb, N);
  spmm_xcd<<<sgrid, 256, 0, stream>>>(offs, cv, hbb, hba, N);

  // fused: preLN = relu(h @ Wt^T + b_t) + x @ Wr^T  (two-phase, 1-D swizzled grid)
  int MB = (N + 127) / 128;
  int NBLK = MB * (FDIM / 128);
  gemm_fused<<<NBLK, 256, 0, stream>>>((const __bf16*)hba, (const __bf16*)xb,
                                       (const __bf16*)wtb, (const __bf16*)wrb,
                                       b_t, preLN, N, NBLK);

  ln_kernel<<<N, 256, 0, stream>>>(preLN, gamma, beta, (float*)d_out);
}